// Round 21
// baseline (491.483 us; speedup 1.0000x reference)
//
#include <hip/hip_runtime.h>
#include <stdint.h>

#define BATCH 8
#define NPTS  16384
#define BN    (BATCH * NPTS)
#define CH    256                 // points per LDS chunk (3 planes, 2 x 12 KB)
#define NCH   (NPTS / CH)         // 64
#define QPB   256                 // 4 waves x 64 queries
#define MARGIN 8.0e-4f            // ~3x over 2*delta (triple-split chain ~1.3e-4)

typedef float f32x16 __attribute__((ext_vector_type(16)));
typedef short s16x8  __attribute__((ext_vector_type(8)));

__device__ __forceinline__ uint16_t bfr(float x) {
    uint32_t u = __float_as_uint(x);
    return (uint16_t)((u + 0x7FFFu + ((u >> 16) & 1u)) >> 16);
}
__device__ __forceinline__ float bff(uint16_t s) {
    return __uint_as_float(((uint32_t)s) << 16);
}
__device__ __forceinline__ void split3(float v, uint16_t* a, uint16_t* b, uint16_t* c) {
    *a = bfr(v);            const float f0 = bff(*a);
    *b = bfr(v - f0);       const float f1 = bff(*b);
    *c = bfr((v - f0) - f1);
}
__device__ __forceinline__ uint32_t pk2(uint16_t lo, uint16_t hi) {
    return (uint32_t)lo | ((uint32_t)hi << 16);
}
// monotone f32 <-> u32 order map (handles negatives from cancellation)
__device__ __forceinline__ uint32_t key32(float d) {
    uint32_t b = __float_as_uint(d);
    return (b & 0x80000000u) ? ~b : (b | 0x80000000u);
}
__device__ __forceinline__ float dec32(uint32_t k) {
    return __uint_as_float((k & 0x80000000u) ? (k ^ 0x80000000u) : ~k);
}

#define F16(M_) M_(0) M_(1) M_(2) M_(3) M_(4) M_(5) M_(6) M_(7) \
                M_(8) M_(9) M_(10) M_(11) M_(12) M_(13) M_(14) M_(15)

#define MIN3(a, b, c) fminf(fminf((a), (b)), (c))

__device__ __forceinline__ float fold16(const f32x16 a) {
    const float u0 = MIN3(a[0],  a[1],  a[2]);
    const float u1 = MIN3(a[3],  a[4],  a[5]);
    const float u2 = MIN3(a[6],  a[7],  a[8]);
    const float u3 = MIN3(a[9],  a[10], a[11]);
    const float u4 = MIN3(a[12], a[13], a[14]);
    const float v0 = MIN3(u0, u1, a[15]);
    const float v1 = MIN3(u2, u3, u4);
    return fminf(v0, v1);
}

// ---- enc: 24 used bf16 K-slots (K=32 chained), point side ----
// P[0..23] = [1,1,1,Sa,Sb,Sc,Y0a,Y0a | Y0a,Y0b,Y0b,Y0c,Y1a,Y1a,Y1a,Y1b |
//             Y1b,Y1c,Y2a,Y2a,Y2a,Y2b,Y2b,Y2c]  (Yd* = split3(-2*yd), S* = split3(ys))
__global__ __launch_bounds__(256) void enc_kernel(
    const float* __restrict__ Y, uint4* __restrict__ enc)
{
#pragma clang fp contract(off)
    const int g = blockIdx.x * 256 + threadIdx.x;     // 0..BN-1
    const int b = g >> 14, p = g & (NPTS - 1);
    const float y0 = Y[(size_t)g * 3 + 0];
    const float y1 = Y[(size_t)g * 3 + 1];
    const float y2 = Y[(size_t)g * 3 + 2];
    const float ys = (y0 * y0 + y1 * y1) + y2 * y2;   // np order (approx side)
    uint16_t Sa, Sb, Sc;    split3(ys, &Sa, &Sb, &Sc);
    uint16_t A0, B0, C0;    split3(-2.0f * y0, &A0, &B0, &C0);
    uint16_t A1, B1, C1;    split3(-2.0f * y1, &A1, &B1, &C1);
    uint16_t A2, B2, C2;    split3(-2.0f * y2, &A2, &B2, &C2);
    const uint16_t ONE = 0x3F80;
    const int ch = p >> 8, pp = p & (CH - 1);
    const size_t base = (size_t)(b * NCH + ch) * (3 * CH) + pp;
    enc[base]          = make_uint4(pk2(ONE, ONE), pk2(ONE, Sa), pk2(Sb, Sc), pk2(A0, A0));
    enc[base + CH]     = make_uint4(pk2(A0, B0), pk2(B0, C0), pk2(A1, A1), pk2(A1, B1));
    enc[base + 2 * CH] = make_uint4(pk2(B1, C1), pk2(A2, A2), pk2(A2, B2), pk2(B2, C2));
}

// decode (dir,batch,kh,xblk); fused ndir=2: grid 2048; sequential: 1024/dir
#define DECODE_DBX() \
    int dir, batch, kh, xblk; \
    { const int g = blockIdx.x; \
      if (ndir == 2) { const int s = 2 * (g & 7) + ((g >> 3) & 1); \
          dir = s >> 3; batch = s & 7; kh = (g >> 4) & 1; xblk = g >> 5; } \
      else { dir = dir0; batch = g & 7; kh = (g >> 3) & 1; xblk = g >> 4; } }

#define STAGE(c, buf) { \
        const uint4* src_ = ep + (size_t)(c) * (3 * CH); \
        _Pragma("unroll") \
        for (int i_ = 0; i_ < 3; ++i_) \
            __builtin_amdgcn_global_load_lds( \
                (const __attribute__((address_space(1))) void*)(src_ + i_ * 256 + tid), \
                (__attribute__((address_space(3))) void*)&lds[buf][i_ * 256 + tid], \
                16, 0, 0); \
    }

// query side: Q[0..23] = [Xa,Xb,Xc,1,1,1,h0,m0 | l0,h0,m0,h0,h1,m1,l1,h1 |
//                         m1,h1,h2,m2,l2,h2,m2,h2]; slots 24-31 zero (hi=1 frag2)
#define MKQFR(qlo, qhi2, qq, qx0v, qx1v, qx2v, qxsv) { \
        const float* xp = Xp + (size_t)(bofs + (qq)) * 3; \
        qx0v = xp[0]; qx1v = xp[1]; qx2v = xp[2]; \
        qxsv = (qx0v * qx0v + qx1v * qx1v) + qx2v * qx2v; \
        uint16_t Xa, Xb, Xc; split3(qxsv, &Xa, &Xb, &Xc); \
        uint16_t h0, m0, l0; split3(qx0v, &h0, &m0, &l0); \
        uint16_t h1, m1, l1; split3(qx1v, &h1, &m1, &l1); \
        uint16_t h2, m2, l2; split3(qx2v, &h2, &m2, &l2); \
        const uint16_t ONE = 0x3F80; \
        if (hi == 0) { \
            qlo[0]=(short)Xa; qlo[1]=(short)Xb; qlo[2]=(short)Xc; qlo[3]=(short)ONE; \
            qlo[4]=(short)ONE; qlo[5]=(short)ONE; qlo[6]=(short)h0; qlo[7]=(short)m0; \
            qhi2[0]=(short)m1; qhi2[1]=(short)h1; qhi2[2]=(short)h2; qhi2[3]=(short)m2; \
            qhi2[4]=(short)l2; qhi2[5]=(short)h2; qhi2[6]=(short)m2; qhi2[7]=(short)h2; \
        } else { \
            qlo[0]=(short)l0; qlo[1]=(short)h0; qlo[2]=(short)m0; qlo[3]=(short)h0; \
            qlo[4]=(short)h1; qlo[5]=(short)m1; qlo[6]=(short)l1; qlo[7]=(short)h1; \
            qhi2[0]=0; qhi2[1]=0; qhi2[2]=0; qhi2[3]=0; \
            qhi2[4]=0; qhi2[5]=0; qhi2[6]=0; qhi2[7]=0; \
        } }

// ============ sweep 1: per-query near-exact min -> mkey ============
__global__ __launch_bounds__(256, 4) void nn_sweep1(
    const float* __restrict__ xyz1, const float* __restrict__ xyz2,
    const uint4* __restrict__ encA, const uint4* __restrict__ encB,
    uint32_t* __restrict__ mkey, int ndir, int dir0)
{
#pragma clang fp contract(off)
    __shared__ uint4 lds[2][3 * CH];                   // 2 x 12 KB

    const int tid = threadIdx.x;
    const int l   = tid & 63;
    const int wv  = tid >> 6;
    const int col = l & 31;
    const int hi  = l >> 5;
    DECODE_DBX()

    const float* Xp = dir ? xyz2 : xyz1;
    const uint4* ep = (dir ? encB : encA) + (size_t)batch * (NCH * 3 * CH);
    const int bofs  = batch * NPTS;
    const int qbase = xblk * QPB + wv * 64;
    const int chalf = NCH / 2;
    const int c0 = kh * chalf, c1 = c0 + chalf;

    const f32x16 zf = {0.f,0.f,0.f,0.f,0.f,0.f,0.f,0.f,
                       0.f,0.f,0.f,0.f,0.f,0.f,0.f,0.f};

    s16x8 q0lo, q0hi, q1lo, q1hi;
    float qa0, qa1, qa2, qas, qb0, qb1, qb2, qbs;
    MKQFR(q0lo, q0hi, qbase + col,      qa0, qa1, qa2, qas)
    MKQFR(q1lo, q1hi, qbase + 32 + col, qb0, qb1, qb2, qbs)
    (void)qa0; (void)qb0; (void)qas; (void)qbs;

    const int ldsb = hi * CH + col;

    float run0 = __builtin_inff(), run1 = __builtin_inff();
    STAGE(c0, 0);
    __syncthreads();
    int cur = 0;
    for (int c = c0; c < c1; ++c) {
        if (c + 1 < c1) STAGE(c + 1, cur ^ 1);
#pragma unroll
        for (int tp = 0; tp < CH / 32; ++tp) {
            const s16x8 pA = *(const s16x8*)&lds[cur][ldsb + tp * 32];
            const s16x8 pC = *(const s16x8*)&lds[cur][2 * CH + tp * 32 + col];
            f32x16 a0 = __builtin_amdgcn_mfma_f32_32x32x16_bf16(pA, q0lo, zf, 0, 0, 0);
            f32x16 a1 = __builtin_amdgcn_mfma_f32_32x32x16_bf16(pA, q1lo, zf, 0, 0, 0);
            a0 = __builtin_amdgcn_mfma_f32_32x32x16_bf16(pC, q0hi, a0, 0, 0, 0);
            a1 = __builtin_amdgcn_mfma_f32_32x32x16_bf16(pC, q1hi, a1, 0, 0, 0);
            run0 = fminf(run0, fold16(a0));
            run1 = fminf(run1, fold16(a1));
        }
        __syncthreads();
        cur ^= 1;
    }
    run0 = fminf(run0, __shfl_xor(run0, 32, 64));
    run1 = fminf(run1, __shfl_xor(run1, 32, 64));
    if (l < 32) {
        uint32_t* mp = mkey + (size_t)dir * BN + bofs + qbase;
        atomicMin(&mp[col],      key32(run0));
        atomicMin(&mp[32 + col], key32(run1));
    }
}

// ====== sweep 2: candidates (near-exact d' <= m'+MARGIN) + exact argmin ======
__global__ __launch_bounds__(256, 4) void nn_sweep2(
    const float* __restrict__ xyz1, const float* __restrict__ xyz2,
    const uint4* __restrict__ encA, const uint4* __restrict__ encB,
    const uint32_t* __restrict__ mkey, unsigned long long* __restrict__ gkeys,
    int ndir, int dir0)
{
#pragma clang fp contract(off)
    __shared__ uint4 lds[2][3 * CH];                   // 2 x 12 KB
    __shared__ unsigned long long keys[QPB];           // 2 KB

    const int tid = threadIdx.x;
    const int l   = tid & 63;
    const int wv  = tid >> 6;
    const int col = l & 31;
    const int hi  = l >> 5;
    DECODE_DBX()

    const float* Xp = dir ? xyz2 : xyz1;
    const float* Yp = dir ? xyz1 : xyz2;
    const uint4* ep = (dir ? encB : encA) + (size_t)batch * (NCH * 3 * CH);
    const int bofs  = batch * NPTS;
    const int qbase = xblk * QPB + wv * 64;
    const int chalf = NCH / 2;
    const int c0 = kh * chalf, c1 = c0 + chalf;

    keys[tid] = ~0ull;

    const f32x16 zf = {0.f,0.f,0.f,0.f,0.f,0.f,0.f,0.f,
                       0.f,0.f,0.f,0.f,0.f,0.f,0.f,0.f};

    // A-side (point) row calibration, packed 16 x 8 bits
    int rowpack[4] = {0, 0, 0, 0};
    {
        s16x8 pa = {0,0,0,0,0,0,0,0}, pb = {0,0,0,0,0,0,0,0};
        if (hi == 0) { pa[0] = (short)bfr((float)col); pb[0] = (short)0x3F80; }
        const f32x16 rowp = __builtin_amdgcn_mfma_f32_32x32x16_bf16(pa, pb, zf, 0, 0, 0);
#define PR(i) rowpack[(i) >> 2] |= ((int)rowp[i] & 0xFF) << (((i) & 3) * 8);
        F16(PR)
#undef PR
    }

    s16x8 q0lo, q0hi, q1lo, q1hi;
    float qa0, qa1, qa2, qas, qb0, qb1, qb2, qbs;
    MKQFR(q0lo, q0hi, qbase + col,      qa0, qa1, qa2, qas)
    MKQFR(q1lo, q1hi, qbase + 32 + col, qb0, qb1, qb2, qbs)

    float thr0, thr1;
    {
        const uint32_t* mp = mkey + (size_t)dir * BN + bofs + qbase;
        thr0 = dec32(mp[col]) + MARGIN;
        thr1 = dec32(mp[32 + col]) + MARGIN;
    }

    const int ldsb = hi * CH + col;

#define HITR(accv, jb, foff, thr, qx0, qx1, qx2, qxs, r) \
        if ((accv)[r] <= (thr)) { \
            const int jc = (jb) + ((rowpack[(r) >> 2] >> (((r) & 3) * 8)) & 0xFF); \
            const float* yq = Yp + (size_t)(bofs + jc) * 3; \
            const float py0 = yq[0], py1 = yq[1], py2 = yq[2]; \
            const float pys = (py0 * py0 + py1 * py1) + py2 * py2; \
            const float dd = ((qxs) - 2.0f * (((qx0) * py0 + (qx1) * py1) + (qx2) * py2)) + pys; \
            atomicMin(&keys[wv * 64 + (foff) + col], \
                      ((unsigned long long)key32(dd) << 32) | (uint32_t)jc); }
#define HIT(accv, jb, foff, thr, qx0, qx1, qx2, qxs) \
        if (fold16(accv) <= (thr)) { \
            HITR(accv, jb, foff, thr, qx0, qx1, qx2, qxs, 0) \
            HITR(accv, jb, foff, thr, qx0, qx1, qx2, qxs, 1) \
            HITR(accv, jb, foff, thr, qx0, qx1, qx2, qxs, 2) \
            HITR(accv, jb, foff, thr, qx0, qx1, qx2, qxs, 3) \
            HITR(accv, jb, foff, thr, qx0, qx1, qx2, qxs, 4) \
            HITR(accv, jb, foff, thr, qx0, qx1, qx2, qxs, 5) \
            HITR(accv, jb, foff, thr, qx0, qx1, qx2, qxs, 6) \
            HITR(accv, jb, foff, thr, qx0, qx1, qx2, qxs, 7) \
            HITR(accv, jb, foff, thr, qx0, qx1, qx2, qxs, 8) \
            HITR(accv, jb, foff, thr, qx0, qx1, qx2, qxs, 9) \
            HITR(accv, jb, foff, thr, qx0, qx1, qx2, qxs, 10) \
            HITR(accv, jb, foff, thr, qx0, qx1, qx2, qxs, 11) \
            HITR(accv, jb, foff, thr, qx0, qx1, qx2, qxs, 12) \
            HITR(accv, jb, foff, thr, qx0, qx1, qx2, qxs, 13) \
            HITR(accv, jb, foff, thr, qx0, qx1, qx2, qxs, 14) \
            HITR(accv, jb, foff, thr, qx0, qx1, qx2, qxs, 15) \
        }

    STAGE(c0, 0);
    __syncthreads();
    int cur = 0;
    for (int c = c0; c < c1; ++c) {
        if (c + 1 < c1) STAGE(c + 1, cur ^ 1);
#pragma unroll
        for (int tp = 0; tp < CH / 32; ++tp) {
            const s16x8 pA = *(const s16x8*)&lds[cur][ldsb + tp * 32];
            const s16x8 pC = *(const s16x8*)&lds[cur][2 * CH + tp * 32 + col];
            const int jb = c * CH + tp * 32;
            f32x16 a0 = __builtin_amdgcn_mfma_f32_32x32x16_bf16(pA, q0lo, zf, 0, 0, 0);
            f32x16 a1 = __builtin_amdgcn_mfma_f32_32x32x16_bf16(pA, q1lo, zf, 0, 0, 0);
            a0 = __builtin_amdgcn_mfma_f32_32x32x16_bf16(pC, q0hi, a0, 0, 0, 0);
            a1 = __builtin_amdgcn_mfma_f32_32x32x16_bf16(pC, q1hi, a1, 0, 0, 0);
            HIT(a0, jb, 0,  thr0, qa0, qa1, qa2, qas)
            HIT(a1, jb, 32, thr1, qb0, qb1, qb2, qbs)
        }
        __syncthreads();
        cur ^= 1;
    }
#undef HIT
#undef HITR

    __syncthreads();
    {
        const unsigned long long m = keys[tid];
        const size_t gq = (size_t)dir * BN + bofs + (size_t)xblk * QPB + tid;
        atomicMin(&gkeys[gq], m);              // merge the two k-halves
    }
}

// ---- final: gkeys -> (dist, idx) ----
__global__ __launch_bounds__(256) void writeout_k(
    const unsigned long long* __restrict__ gkeys, float* __restrict__ out)
{
    const size_t i = (size_t)blockIdx.x * 256 + threadIdx.x;   // 0..2*BN-1
    const unsigned long long m = gkeys[i];
    const int dir = (int)(i / BN);
    const size_t q = i - (size_t)dir * BN;
    out[(size_t)dir * BN + q]       = dec32((uint32_t)(m >> 32));
    out[(size_t)(2 + dir) * BN + q] = (float)(uint32_t)(m & 0xFFFFFFFFu);
}

extern "C" void kernel_launch(void* const* d_in, const int* in_sizes, int n_in,
                              void* d_out, int out_size, void* d_ws, size_t ws_size,
                              hipStream_t stream) {
    const float* xyz1 = (const float*)d_in[0];
    const float* xyz2 = (const float*)d_in[1];
    float* out = (float*)d_out;

    if (ws_size >= (size_t)16 * 1024 * 1024) {
        // fused: encA(6) + encB(6) + mkey(1) + gkeys(2) = 15 MiB
        uint4*    encA = (uint4*)d_ws;
        uint4*    encB = encA + (size_t)3 * BN;
        uint32_t* mkey = (uint32_t*)(encB + (size_t)3 * BN);
        unsigned long long* gkeys = (unsigned long long*)(mkey + (size_t)2 * BN);

        enc_kernel<<<BN / 256, 256, 0, stream>>>(xyz2, encA);
        enc_kernel<<<BN / 256, 256, 0, stream>>>(xyz1, encB);
        hipMemsetAsync(mkey, 0xFF, (size_t)3 * 1024 * 1024, stream);
        nn_sweep1<<<2048, 256, 0, stream>>>(xyz1, xyz2, encA, encB, mkey, 2, 0);
        nn_sweep2<<<2048, 256, 0, stream>>>(xyz1, xyz2, encA, encB, mkey, gkeys, 2, 0);
        writeout_k<<<(2 * BN) / 256, 256, 0, stream>>>(gkeys, out);
    } else {
        // sequential: enc(6) + mkey(1) + gkeys(2) = 9 MiB (ws >= 11 MiB proven)
        uint4*    enc  = (uint4*)d_ws;
        uint32_t* mkey = (uint32_t*)(enc + (size_t)3 * BN);
        unsigned long long* gkeys = (unsigned long long*)(mkey + (size_t)2 * BN);

        hipMemsetAsync(mkey, 0xFF, (size_t)3 * 1024 * 1024, stream);
        enc_kernel<<<BN / 256, 256, 0, stream>>>(xyz2, enc);
        nn_sweep1<<<1024, 256, 0, stream>>>(xyz1, xyz2, enc, enc, mkey, 1, 0);
        nn_sweep2<<<1024, 256, 0, stream>>>(xyz1, xyz2, enc, enc, mkey, gkeys, 1, 0);
        enc_kernel<<<BN / 256, 256, 0, stream>>>(xyz1, enc);
        nn_sweep1<<<1024, 256, 0, stream>>>(xyz1, xyz2, enc, enc, mkey, 1, 1);
        nn_sweep2<<<1024, 256, 0, stream>>>(xyz1, xyz2, enc, enc, mkey, gkeys, 1, 1);
        writeout_k<<<(2 * BN) / 256, 256, 0, stream>>>(gkeys, out);
    }
}

// Round 22
// 413.754 us; speedup vs baseline: 1.1879x; 1.1879x over previous
//
#include <hip/hip_runtime.h>
#include <stdint.h>

#define BATCH 8
#define NPTS  16384
#define BN    (BATCH * NPTS)
#define CH    256                 // points per LDS chunk (2 x 8 KB buffers)
#define NCH   (NPTS / CH)         // 64
#define QPB   256                 // 4 waves x 64 queries (2 query B-frags/wave)
#define MARGIN 4.0e-3f            // >= 2.5x worst-stack approx error (~1.6e-3)

typedef float f32x16 __attribute__((ext_vector_type(16)));
typedef short s16x8  __attribute__((ext_vector_type(8)));

__device__ __forceinline__ uint16_t bfr(float x) {
    uint32_t u = __float_as_uint(x);
    return (uint16_t)((u + 0x7FFFu + ((u >> 16) & 1u)) >> 16);
}
__device__ __forceinline__ float bff(uint16_t s) {
    return __uint_as_float(((uint32_t)s) << 16);
}
__device__ __forceinline__ void split2(float v, uint16_t* a, uint16_t* b) {
    *a = bfr(v); *b = bfr(v - bff(*a));
}
__device__ __forceinline__ uint32_t pk2(uint16_t lo, uint16_t hi) {
    return (uint32_t)lo | ((uint32_t)hi << 16);
}
// monotone f32 <-> u32 order map (handles negatives from cancellation)
__device__ __forceinline__ uint32_t key32(float d) {
    uint32_t b = __float_as_uint(d);
    return (b & 0x80000000u) ? ~b : (b | 0x80000000u);
}
__device__ __forceinline__ float dec32(uint32_t k) {
    return __uint_as_float((k & 0x80000000u) ? (k ^ 0x80000000u) : ~k);
}

#define F16(M_) M_(0) M_(1) M_(2) M_(3) M_(4) M_(5) M_(6) M_(7) \
                M_(8) M_(9) M_(10) M_(11) M_(12) M_(13) M_(14) M_(15)

#define MIN3(a, b, c) fminf(fminf((a), (b)), (c))

__device__ __forceinline__ float fold16(const f32x16 a) {
    const float u0 = MIN3(a[0],  a[1],  a[2]);
    const float u1 = MIN3(a[3],  a[4],  a[5]);
    const float u2 = MIN3(a[6],  a[7],  a[8]);
    const float u3 = MIN3(a[9],  a[10], a[11]);
    const float u4 = MIN3(a[12], a[13], a[14]);
    const float v0 = MIN3(u0, u1, a[15]);
    const float v1 = MIN3(u2, u3, u4);
    return fminf(v0, v1);
}

// ---- enc: 16 bf16 K-slots (double-split) + y4 fast-eval array ----
// enc slots = [1,1,Ya,Yb, H0,M0,H0,M0 | H1,M1,H1,M1, H2,M2,H2,M2]
// y4[g] = (y0, y1, y2, ys) f32, ys in exact np order (used by HIT walk)
__global__ __launch_bounds__(256) void enc_kernel(
    const float* __restrict__ Y, uint4* __restrict__ enc,
    float4* __restrict__ y4)
{
#pragma clang fp contract(off)
    const int g = blockIdx.x * 256 + threadIdx.x;     // 0..BN-1
    const int b = g >> 14, p = g & (NPTS - 1);
    const float y0 = Y[(size_t)g * 3 + 0];
    const float y1 = Y[(size_t)g * 3 + 1];
    const float y2 = Y[(size_t)g * 3 + 2];
    const float ys = (y0 * y0 + y1 * y1) + y2 * y2;   // np order
    uint16_t Ya, Yb; split2(ys, &Ya, &Yb);
    uint16_t H0, M0; split2(-2.0f * y0, &H0, &M0);
    uint16_t H1, M1; split2(-2.0f * y1, &H1, &M1);
    uint16_t H2, M2; split2(-2.0f * y2, &H2, &M2);
    const uint16_t ONE = 0x3F80;
    const int ch = p >> 8, pp = p & (CH - 1);
    const size_t base = (size_t)(b * NCH + ch) * (2 * CH) + pp;
    enc[base]      = make_uint4(pk2(ONE, ONE), pk2(Ya, Yb), pk2(H0, M0), pk2(H0, M0));
    enc[base + CH] = make_uint4(pk2(H1, M1), pk2(H1, M1), pk2(H2, M2), pk2(H2, M2));
    y4[g] = make_float4(y0, y1, y2, ys);
}

// decode (dir,batch,kh,xblk); ndir=2: grid 2048; ndir=1: grid 1024
#define DECODE_DBX() \
    int dir, batch, kh, xblk; \
    { const int g = blockIdx.x; \
      if (ndir == 2) { const int s = 2 * (g & 7) + ((g >> 3) & 1); \
          dir = s >> 3; batch = s & 7; kh = (g >> 4) & 1; xblk = g >> 5; } \
      else { dir = dir0; batch = g & 7; kh = (g >> 3) & 1; xblk = g >> 4; } }

#define STAGE(c, buf) { \
        const uint4* src_ = ep + (size_t)(c) * (2 * CH); \
        _Pragma("unroll") \
        for (int i_ = 0; i_ < 2; ++i_) \
            __builtin_amdgcn_global_load_lds( \
                (const __attribute__((address_space(1))) void*)(src_ + i_ * 256 + tid), \
                (__attribute__((address_space(3))) void*)&lds[buf][i_ * 256 + tid], \
                16, 0, 0); \
    }

#define MKQFR(dst, qq, qx0v, qx1v, qx2v, qxsv) { \
        const float* xp = Xp + (size_t)(bofs + (qq)) * 3; \
        qx0v = xp[0]; qx1v = xp[1]; qx2v = xp[2]; \
        qxsv = (qx0v * qx0v + qx1v * qx1v) + qx2v * qx2v; \
        uint16_t Xa, Xb; split2(qxsv, &Xa, &Xb); \
        uint16_t h0, m0; split2(qx0v, &h0, &m0); \
        uint16_t h1, m1; split2(qx1v, &h1, &m1); \
        uint16_t h2, m2; split2(qx2v, &h2, &m2); \
        const uint16_t ONE = 0x3F80; \
        if (hi == 0) { \
            dst[0]=(short)Xa; dst[1]=(short)Xb; dst[2]=(short)ONE; dst[3]=(short)ONE; \
            dst[4]=(short)h0; dst[5]=(short)h0; dst[6]=(short)m0;  dst[7]=(short)m0; \
        } else { \
            dst[0]=(short)h1; dst[1]=(short)h1; dst[2]=(short)m1;  dst[3]=(short)m1; \
            dst[4]=(short)h2; dst[5]=(short)h2; dst[6]=(short)m2;  dst[7]=(short)m2; \
        } }

// ===== fused single-sweep: online threshold + candidate walk + exact argmin =====
// run/thr evolve monotonically downward; flagged set is a SUPERSET of the
// 2-sweep candidate set (thr_t >= final m'+MARGIN), so exactness is preserved:
// every candidate is re-evaluated with the bit-exact reference f32 chain and
// merged via packed-key atomicMin (first-occurrence argmin, deterministic).
__global__ __launch_bounds__(256, 4) void nn_fused(
    const float* __restrict__ xyz1, const float* __restrict__ xyz2,
    const uint4* __restrict__ encA, const uint4* __restrict__ encB,
    const float4* __restrict__ y4A, const float4* __restrict__ y4B,
    unsigned long long* __restrict__ gkeys, int ndir, int dir0)
{
#pragma clang fp contract(off)
    __shared__ uint4 lds[2][2 * CH];                   // 2 x 8 KB
    __shared__ unsigned long long keys[QPB];           // 2 KB

    const int tid = threadIdx.x;
    const int l   = tid & 63;
    const int wv  = tid >> 6;
    const int col = l & 31;
    const int hi  = l >> 5;
    DECODE_DBX()

    const float*  Xp = dir ? xyz2 : xyz1;
    const uint4*  ep = (dir ? encB : encA) + (size_t)batch * (NCH * 2 * CH);
    const float4* Y4 = (dir ? y4B : y4A) + (size_t)batch * NPTS;
    const int bofs  = batch * NPTS;
    const int qbase = xblk * QPB + wv * 64;
    const int chalf = NCH / 2;
    const int c0 = kh * chalf, c1 = c0 + chalf;

    keys[tid] = ~0ull;

    const f32x16 zf = {0.f,0.f,0.f,0.f,0.f,0.f,0.f,0.f,
                       0.f,0.f,0.f,0.f,0.f,0.f,0.f,0.f};

    // A-side (point) row calibration, packed 16 x 8 bits
    int rowpack[4] = {0, 0, 0, 0};
    {
        s16x8 pa = {0,0,0,0,0,0,0,0}, pb = {0,0,0,0,0,0,0,0};
        if (hi == 0) { pa[0] = (short)bfr((float)col); pb[0] = (short)0x3F80; }
        const f32x16 rowp = __builtin_amdgcn_mfma_f32_32x32x16_bf16(pa, pb, zf, 0, 0, 0);
#define PR(i) rowpack[(i) >> 2] |= ((int)rowp[i] & 0xFF) << (((i) & 3) * 8);
        F16(PR)
#undef PR
    }

    s16x8 qfr0, qfr1;
    float qa0, qa1, qa2, qas, qb0, qb1, qb2, qbs;
    MKQFR(qfr0, qbase + col,      qa0, qa1, qa2, qas)
    MKQFR(qfr1, qbase + 32 + col, qb0, qb1, qb2, qbs)

    const int ldsb = hi * CH + col;

    float run0 = __builtin_inff(), run1 = __builtin_inff();

    // ---- seed: fold-only pass over chunk c0 (stays in buffer 0) ----
    STAGE(c0, 0);
    __syncthreads();
#pragma unroll
    for (int tp = 0; tp < CH / 32; ++tp) {
        const s16x8 pA = *(const s16x8*)&lds[0][ldsb + tp * 32];
        const f32x16 a0 = __builtin_amdgcn_mfma_f32_32x32x16_bf16(pA, qfr0, zf, 0, 0, 0);
        run0 = fminf(run0, fold16(a0));
        const f32x16 a1 = __builtin_amdgcn_mfma_f32_32x32x16_bf16(pA, qfr1, zf, 0, 0, 0);
        run1 = fminf(run1, fold16(a1));
    }
    run0 = fminf(run0, __shfl_xor(run0, 32, 64));
    run1 = fminf(run1, __shfl_xor(run1, 32, 64));

#define HITR(accv, jb, foff, thr, qx0, qx1, qx2, qxs, r) \
        if ((accv)[r] <= (thr)) { \
            const int jc = (jb) + ((rowpack[(r) >> 2] >> (((r) & 3) * 8)) & 0xFF); \
            const float4 yv = Y4[jc]; \
            const float dd = ((qxs) - 2.0f * (((qx0) * yv.x + (qx1) * yv.y) + (qx2) * yv.z)) + yv.w; \
            atomicMin(&keys[wv * 64 + (foff) + col], \
                      ((unsigned long long)key32(dd) << 32) | (uint32_t)jc); }
#define HIT(accv, jb, foff, thr, qx0, qx1, qx2, qxs) \
        { \
            HITR(accv, jb, foff, thr, qx0, qx1, qx2, qxs, 0) \
            HITR(accv, jb, foff, thr, qx0, qx1, qx2, qxs, 1) \
            HITR(accv, jb, foff, thr, qx0, qx1, qx2, qxs, 2) \
            HITR(accv, jb, foff, thr, qx0, qx1, qx2, qxs, 3) \
            HITR(accv, jb, foff, thr, qx0, qx1, qx2, qxs, 4) \
            HITR(accv, jb, foff, thr, qx0, qx1, qx2, qxs, 5) \
            HITR(accv, jb, foff, thr, qx0, qx1, qx2, qxs, 6) \
            HITR(accv, jb, foff, thr, qx0, qx1, qx2, qxs, 7) \
            HITR(accv, jb, foff, thr, qx0, qx1, qx2, qxs, 8) \
            HITR(accv, jb, foff, thr, qx0, qx1, qx2, qxs, 9) \
            HITR(accv, jb, foff, thr, qx0, qx1, qx2, qxs, 10) \
            HITR(accv, jb, foff, thr, qx0, qx1, qx2, qxs, 11) \
            HITR(accv, jb, foff, thr, qx0, qx1, qx2, qxs, 12) \
            HITR(accv, jb, foff, thr, qx0, qx1, qx2, qxs, 13) \
            HITR(accv, jb, foff, thr, qx0, qx1, qx2, qxs, 14) \
            HITR(accv, jb, foff, thr, qx0, qx1, qx2, qxs, 15) \
        }

    // ---- main pass: all chunks with online guard (chunk c0 already staged) ----
    int cur = 0;
    for (int c = c0; c < c1; ++c) {
        if (c + 1 < c1) STAGE(c + 1, cur ^ 1);
#pragma unroll
        for (int tp = 0; tp < CH / 32; ++tp) {
            const s16x8 pA = *(const s16x8*)&lds[cur][ldsb + tp * 32];
            const int jb = c * CH + tp * 32;
            {
                const f32x16 a0 = __builtin_amdgcn_mfma_f32_32x32x16_bf16(pA, qfr0, zf, 0, 0, 0);
                const float f0 = fold16(a0);
                run0 = fminf(run0, f0);
                const float t0v = run0 + MARGIN;
                if (f0 <= t0v) HIT(a0, jb, 0, t0v, qa0, qa1, qa2, qas)
            }
            {
                const f32x16 a1 = __builtin_amdgcn_mfma_f32_32x32x16_bf16(pA, qfr1, zf, 0, 0, 0);
                const float f1 = fold16(a1);
                run1 = fminf(run1, f1);
                const float t1v = run1 + MARGIN;
                if (f1 <= t1v) HIT(a1, jb, 32, t1v, qb0, qb1, qb2, qbs)
            }
        }
        // tighten across hi-halves once per chunk (cheap, shrinks thr)
        run0 = fminf(run0, __shfl_xor(run0, 32, 64));
        run1 = fminf(run1, __shfl_xor(run1, 32, 64));
        __syncthreads();
        cur ^= 1;
    }
#undef HIT
#undef HITR

    __syncthreads();
    {
        const unsigned long long m = keys[tid];
        const size_t gq = (size_t)dir * BN + bofs + (size_t)xblk * QPB + tid;
        atomicMin(&gkeys[gq], m);              // merge the two k-halves
    }
}

// ---- final: gkeys -> (dist, idx) ----
__global__ __launch_bounds__(256) void writeout_k(
    const unsigned long long* __restrict__ gkeys, float* __restrict__ out)
{
    const size_t i = (size_t)blockIdx.x * 256 + threadIdx.x;   // 0..2*BN-1
    const unsigned long long m = gkeys[i];
    const int dir = (int)(i / BN);
    const size_t q = i - (size_t)dir * BN;
    out[(size_t)dir * BN + q]       = dec32((uint32_t)(m >> 32));
    out[(size_t)(2 + dir) * BN + q] = (float)(uint32_t)(m & 0xFFFFFFFFu);
}

extern "C" void kernel_launch(void* const* d_in, const int* in_sizes, int n_in,
                              void* d_out, int out_size, void* d_ws, size_t ws_size,
                              hipStream_t stream) {
    const float* xyz1 = (const float*)d_in[0];
    const float* xyz2 = (const float*)d_in[1];
    float* out = (float*)d_out;

    if (ws_size >= (size_t)15 * 1024 * 1024) {
        // fused: encA(4) + encB(4) + y4A(2) + y4B(2) + gkeys(2) = 14 MiB
        uint4*  encA = (uint4*)d_ws;
        uint4*  encB = encA + (size_t)2 * BN;
        float4* y4A  = (float4*)(encB + (size_t)2 * BN);
        float4* y4B  = y4A + BN;
        unsigned long long* gkeys = (unsigned long long*)(y4B + BN);

        enc_kernel<<<BN / 256, 256, 0, stream>>>(xyz2, encA, y4A);
        enc_kernel<<<BN / 256, 256, 0, stream>>>(xyz1, encB, y4B);
        hipMemsetAsync(gkeys, 0xFF, (size_t)2 * 1024 * 1024, stream);
        nn_fused<<<2048, 256, 0, stream>>>(xyz1, xyz2, encA, encB, y4A, y4B,
                                           gkeys, 2, 0);
        writeout_k<<<(2 * BN) / 256, 256, 0, stream>>>(gkeys, out);
    } else {
        // sequential: enc(4) + y4(2) + gkeys(2) = 8 MiB (ws >= 11 MiB proven R19)
        uint4*  enc = (uint4*)d_ws;
        float4* y4  = (float4*)(enc + (size_t)2 * BN);
        unsigned long long* gkeys = (unsigned long long*)(y4 + BN);

        hipMemsetAsync(gkeys, 0xFF, (size_t)2 * 1024 * 1024, stream);
        enc_kernel<<<BN / 256, 256, 0, stream>>>(xyz2, enc, y4);
        nn_fused<<<1024, 256, 0, stream>>>(xyz1, xyz2, enc, enc, y4, y4,
                                           gkeys, 1, 0);
        enc_kernel<<<BN / 256, 256, 0, stream>>>(xyz1, enc, y4);
        nn_fused<<<1024, 256, 0, stream>>>(xyz1, xyz2, enc, enc, y4, y4,
                                           gkeys, 1, 1);
        writeout_k<<<(2 * BN) / 256, 256, 0, stream>>>(gkeys, out);
    }
}

// Round 23
// 373.488 us; speedup vs baseline: 1.3159x; 1.1078x over previous
//
#include <hip/hip_runtime.h>
#include <stdint.h>

#define BATCH 8
#define NPTS  16384
#define BN    (BATCH * NPTS)
#define CH    256                 // points per LDS chunk (2 x 8 KB buffers)
#define NCH   (NPTS / CH)         // 64
#define QPB   256                 // 4 waves x 64 queries (2 query B-frags/wave)
#define MARGIN 3.0e-3f            // > 2*delta_worst (2.6e-3), deterministic bound

typedef float f32x16 __attribute__((ext_vector_type(16)));
typedef short s16x8  __attribute__((ext_vector_type(8)));

__device__ __forceinline__ uint16_t bfr(float x) {
    uint32_t u = __float_as_uint(x);
    return (uint16_t)((u + 0x7FFFu + ((u >> 16) & 1u)) >> 16);
}
__device__ __forceinline__ float bff(uint16_t s) {
    return __uint_as_float(((uint32_t)s) << 16);
}
__device__ __forceinline__ void split2(float v, uint16_t* a, uint16_t* b) {
    *a = bfr(v); *b = bfr(v - bff(*a));
}
__device__ __forceinline__ uint32_t pk2(uint16_t lo, uint16_t hi) {
    return (uint32_t)lo | ((uint32_t)hi << 16);
}
// monotone f32 <-> u32 order map (handles negatives from cancellation)
__device__ __forceinline__ uint32_t key32(float d) {
    uint32_t b = __float_as_uint(d);
    return (b & 0x80000000u) ? ~b : (b | 0x80000000u);
}
__device__ __forceinline__ float dec32(uint32_t k) {
    return __uint_as_float((k & 0x80000000u) ? (k ^ 0x80000000u) : ~k);
}

#define F16(M_) M_(0) M_(1) M_(2) M_(3) M_(4) M_(5) M_(6) M_(7) \
                M_(8) M_(9) M_(10) M_(11) M_(12) M_(13) M_(14) M_(15)

#define MIN3(a, b, c) fminf(fminf((a), (b)), (c))

__device__ __forceinline__ float fold16(const f32x16 a) {
    const float u0 = MIN3(a[0],  a[1],  a[2]);
    const float u1 = MIN3(a[3],  a[4],  a[5]);
    const float u2 = MIN3(a[6],  a[7],  a[8]);
    const float u3 = MIN3(a[9],  a[10], a[11]);
    const float u4 = MIN3(a[12], a[13], a[14]);
    const float v0 = MIN3(u0, u1, a[15]);
    const float v1 = MIN3(u2, u3, u4);
    return fminf(v0, v1);
}

// ---- enc: 16 bf16 K-slots (double-split) + y4 fast-eval array ----
// enc slots = [1,1,Ya,Yb, H0,M0,H0,M0 | H1,M1,H1,M1, H2,M2,H2,M2]
// y4[g] = (y0, y1, y2, ys) f32, ys in exact np order (used by HIT walk)
__global__ __launch_bounds__(256) void enc_kernel(
    const float* __restrict__ Y, uint4* __restrict__ enc,
    float4* __restrict__ y4)
{
#pragma clang fp contract(off)
    const int g = blockIdx.x * 256 + threadIdx.x;     // 0..BN-1
    const int b = g >> 14, p = g & (NPTS - 1);
    const float y0 = Y[(size_t)g * 3 + 0];
    const float y1 = Y[(size_t)g * 3 + 1];
    const float y2 = Y[(size_t)g * 3 + 2];
    const float ys = (y0 * y0 + y1 * y1) + y2 * y2;   // np order
    uint16_t Ya, Yb; split2(ys, &Ya, &Yb);
    uint16_t H0, M0; split2(-2.0f * y0, &H0, &M0);
    uint16_t H1, M1; split2(-2.0f * y1, &H1, &M1);
    uint16_t H2, M2; split2(-2.0f * y2, &H2, &M2);
    const uint16_t ONE = 0x3F80;
    const int ch = p >> 8, pp = p & (CH - 1);
    const size_t base = (size_t)(b * NCH + ch) * (2 * CH) + pp;
    enc[base]      = make_uint4(pk2(ONE, ONE), pk2(Ya, Yb), pk2(H0, M0), pk2(H0, M0));
    enc[base + CH] = make_uint4(pk2(H1, M1), pk2(H1, M1), pk2(H2, M2), pk2(H2, M2));
    y4[g] = make_float4(y0, y1, y2, ys);
}

// decode (dir,batch,kh,xblk); ksplit=2: grid 2048, each block half the points
#define DECODE_DBX() \
    int dir, batch, kh, xblk; \
    { const int g = blockIdx.x; \
      const int s = 2 * (g & 7) + ((g >> 3) & 1); \
      dir = s >> 3; batch = s & 7; \
      if (ksplit == 2) { kh = (g >> 4) & 1; xblk = g >> 5; } \
      else             { kh = 0;            xblk = g >> 4; } }

#define STAGE(c, buf) { \
        const uint4* src_ = ep + (size_t)(c) * (2 * CH); \
        _Pragma("unroll") \
        for (int i_ = 0; i_ < 2; ++i_) \
            __builtin_amdgcn_global_load_lds( \
                (const __attribute__((address_space(1))) void*)(src_ + i_ * 256 + tid), \
                (__attribute__((address_space(3))) void*)&lds[buf][i_ * 256 + tid], \
                16, 0, 0); \
    }

#define MKQFR(dst, qq, qx0v, qx1v, qx2v, qxsv) { \
        const float* xp = Xp + (size_t)(bofs + (qq)) * 3; \
        qx0v = xp[0]; qx1v = xp[1]; qx2v = xp[2]; \
        qxsv = (qx0v * qx0v + qx1v * qx1v) + qx2v * qx2v; \
        uint16_t Xa, Xb; split2(qxsv, &Xa, &Xb); \
        uint16_t h0, m0; split2(qx0v, &h0, &m0); \
        uint16_t h1, m1; split2(qx1v, &h1, &m1); \
        uint16_t h2, m2; split2(qx2v, &h2, &m2); \
        const uint16_t ONE = 0x3F80; \
        if (hi == 0) { \
            dst[0]=(short)Xa; dst[1]=(short)Xb; dst[2]=(short)ONE; dst[3]=(short)ONE; \
            dst[4]=(short)h0; dst[5]=(short)h0; dst[6]=(short)m0;  dst[7]=(short)m0; \
        } else { \
            dst[0]=(short)h1; dst[1]=(short)h1; dst[2]=(short)m1;  dst[3]=(short)m1; \
            dst[4]=(short)h2; dst[5]=(short)h2; dst[6]=(short)m2;  dst[7]=(short)m2; \
        } }

// ============ sweep 1: per-query approx min -> mkey (u32 order keys) ============
__global__ __launch_bounds__(256, 4) void nn_sweep1(
    const float* __restrict__ xyz1, const float* __restrict__ xyz2,
    const uint4* __restrict__ encA, const uint4* __restrict__ encB,
    uint32_t* __restrict__ mkey, int ksplit)
{
#pragma clang fp contract(off)
    __shared__ uint4 lds[2][2 * CH];                   // 2 x 8 KB

    const int tid = threadIdx.x;
    const int l   = tid & 63;
    const int wv  = tid >> 6;
    const int col = l & 31;
    const int hi  = l >> 5;
    DECODE_DBX()

    const float* Xp = dir ? xyz2 : xyz1;
    const uint4* ep = (dir ? encB : encA) + (size_t)batch * (NCH * 2 * CH);
    const int bofs  = batch * NPTS;
    const int qbase = xblk * QPB + wv * 64;
    const int chalf = NCH / ksplit;
    const int c0 = kh * chalf, c1 = c0 + chalf;

    const f32x16 zf = {0.f,0.f,0.f,0.f,0.f,0.f,0.f,0.f,
                       0.f,0.f,0.f,0.f,0.f,0.f,0.f,0.f};

    s16x8 qfr0, qfr1;
    float qa0, qa1, qa2, qas, qb0, qb1, qb2, qbs;
    MKQFR(qfr0, qbase + col,      qa0, qa1, qa2, qas)
    MKQFR(qfr1, qbase + 32 + col, qb0, qb1, qb2, qbs)
    (void)qa0; (void)qb0;

    const int ldsb = hi * CH + col;

    float run0 = __builtin_inff(), run1 = __builtin_inff();
    STAGE(c0, 0);
    __syncthreads();
    int cur = 0;
    for (int c = c0; c < c1; ++c) {
        if (c + 1 < c1) STAGE(c + 1, cur ^ 1);
#pragma unroll
        for (int tp = 0; tp < CH / 32; ++tp) {
            const s16x8 pA = *(const s16x8*)&lds[cur][ldsb + tp * 32];
            const f32x16 a0 = __builtin_amdgcn_mfma_f32_32x32x16_bf16(pA, qfr0, zf, 0, 0, 0);
            run0 = fminf(run0, fold16(a0));
            const f32x16 a1 = __builtin_amdgcn_mfma_f32_32x32x16_bf16(pA, qfr1, zf, 0, 0, 0);
            run1 = fminf(run1, fold16(a1));
        }
        __syncthreads();
        cur ^= 1;
    }
    run0 = fminf(run0, __shfl_xor(run0, 32, 64));
    run1 = fminf(run1, __shfl_xor(run1, 32, 64));
    if (l < 32) {
        uint32_t* mp = mkey + (size_t)dir * BN + bofs + qbase;
        atomicMin(&mp[col],      key32(run0));
        atomicMin(&mp[32 + col], key32(run1));
    }
}

// ====== sweep 2: candidates (approx d <= m'+MARGIN) + exact argmin ======
__global__ __launch_bounds__(256, 4) void nn_sweep2(
    const float* __restrict__ xyz1, const float* __restrict__ xyz2,
    const uint4* __restrict__ encA, const uint4* __restrict__ encB,
    const float4* __restrict__ y4A, const float4* __restrict__ y4B,
    const uint32_t* __restrict__ mkey, unsigned long long* __restrict__ gkeys,
    float* __restrict__ out, int ksplit)
{
#pragma clang fp contract(off)
    __shared__ uint4 lds[2][2 * CH];                   // 2 x 8 KB
    __shared__ unsigned long long keys[QPB];           // 2 KB

    const int tid = threadIdx.x;
    const int l   = tid & 63;
    const int wv  = tid >> 6;
    const int col = l & 31;
    const int hi  = l >> 5;
    DECODE_DBX()

    const float*  Xp = dir ? xyz2 : xyz1;
    const uint4*  ep = (dir ? encB : encA) + (size_t)batch * (NCH * 2 * CH);
    const float4* Y4 = (dir ? y4B : y4A) + (size_t)batch * NPTS;
    const int bofs  = batch * NPTS;
    const int qbase = xblk * QPB + wv * 64;
    const int chalf = NCH / ksplit;
    const int c0 = kh * chalf, c1 = c0 + chalf;

    keys[tid] = ~0ull;

    const f32x16 zf = {0.f,0.f,0.f,0.f,0.f,0.f,0.f,0.f,
                       0.f,0.f,0.f,0.f,0.f,0.f,0.f,0.f};

    // A-side (point) row calibration, packed 16 x 8 bits
    int rowpack[4] = {0, 0, 0, 0};
    {
        s16x8 pa = {0,0,0,0,0,0,0,0}, pb = {0,0,0,0,0,0,0,0};
        if (hi == 0) { pa[0] = (short)bfr((float)col); pb[0] = (short)0x3F80; }
        const f32x16 rowp = __builtin_amdgcn_mfma_f32_32x32x16_bf16(pa, pb, zf, 0, 0, 0);
#define PR(i) rowpack[(i) >> 2] |= ((int)rowp[i] & 0xFF) << (((i) & 3) * 8);
        F16(PR)
#undef PR
    }

    s16x8 qfr0, qfr1;
    float qa0, qa1, qa2, qas, qb0, qb1, qb2, qbs;
    MKQFR(qfr0, qbase + col,      qa0, qa1, qa2, qas)
    MKQFR(qfr1, qbase + 32 + col, qb0, qb1, qb2, qbs)

    float thr0, thr1;
    {
        const uint32_t* mp = mkey + (size_t)dir * BN + bofs + qbase;
        thr0 = dec32(mp[col]) + MARGIN;
        thr1 = dec32(mp[32 + col]) + MARGIN;
    }

    const int ldsb = hi * CH + col;

#define HITR(accv, jb, foff, thr, qx0, qx1, qx2, qxs, r) \
        if ((accv)[r] <= (thr)) { \
            const int jc = (jb) + ((rowpack[(r) >> 2] >> (((r) & 3) * 8)) & 0xFF); \
            const float4 yv = Y4[jc]; \
            const float dd = ((qxs) - 2.0f * (((qx0) * yv.x + (qx1) * yv.y) + (qx2) * yv.z)) + yv.w; \
            atomicMin(&keys[wv * 64 + (foff) + col], \
                      ((unsigned long long)key32(dd) << 32) | (uint32_t)jc); }
#define HIT(accv, jb, foff, thr, qx0, qx1, qx2, qxs) \
        if (fold16(accv) <= (thr)) { \
            HITR(accv, jb, foff, thr, qx0, qx1, qx2, qxs, 0) \
            HITR(accv, jb, foff, thr, qx0, qx1, qx2, qxs, 1) \
            HITR(accv, jb, foff, thr, qx0, qx1, qx2, qxs, 2) \
            HITR(accv, jb, foff, thr, qx0, qx1, qx2, qxs, 3) \
            HITR(accv, jb, foff, thr, qx0, qx1, qx2, qxs, 4) \
            HITR(accv, jb, foff, thr, qx0, qx1, qx2, qxs, 5) \
            HITR(accv, jb, foff, thr, qx0, qx1, qx2, qxs, 6) \
            HITR(accv, jb, foff, thr, qx0, qx1, qx2, qxs, 7) \
            HITR(accv, jb, foff, thr, qx0, qx1, qx2, qxs, 8) \
            HITR(accv, jb, foff, thr, qx0, qx1, qx2, qxs, 9) \
            HITR(accv, jb, foff, thr, qx0, qx1, qx2, qxs, 10) \
            HITR(accv, jb, foff, thr, qx0, qx1, qx2, qxs, 11) \
            HITR(accv, jb, foff, thr, qx0, qx1, qx2, qxs, 12) \
            HITR(accv, jb, foff, thr, qx0, qx1, qx2, qxs, 13) \
            HITR(accv, jb, foff, thr, qx0, qx1, qx2, qxs, 14) \
            HITR(accv, jb, foff, thr, qx0, qx1, qx2, qxs, 15) \
        }

    STAGE(c0, 0);
    __syncthreads();
    int cur = 0;
    for (int c = c0; c < c1; ++c) {
        if (c + 1 < c1) STAGE(c + 1, cur ^ 1);
#pragma unroll
        for (int tp = 0; tp < CH / 32; ++tp) {
            const s16x8 pA = *(const s16x8*)&lds[cur][ldsb + tp * 32];
            const int jb = c * CH + tp * 32;
            const f32x16 a0 = __builtin_amdgcn_mfma_f32_32x32x16_bf16(pA, qfr0, zf, 0, 0, 0);
            HIT(a0, jb, 0, thr0, qa0, qa1, qa2, qas)
            const f32x16 a1 = __builtin_amdgcn_mfma_f32_32x32x16_bf16(pA, qfr1, zf, 0, 0, 0);
            HIT(a1, jb, 32, thr1, qb0, qb1, qb2, qbs)
        }
        __syncthreads();
        cur ^= 1;
    }
#undef HIT
#undef HITR

    __syncthreads();
    {
        const unsigned long long m = keys[tid];
        const size_t gq = (size_t)dir * BN + bofs + (size_t)xblk * QPB + tid;
        if (ksplit == 2) {
            atomicMin(&gkeys[gq], m);          // merge the two k-halves
        } else {
            const uint32_t k32 = (uint32_t)(m >> 32);
            const size_t q = (size_t)bofs + (size_t)xblk * QPB + tid;
            out[(size_t)dir * BN + q]       = dec32(k32);
            out[(size_t)(2 + dir) * BN + q] = (float)(uint32_t)(m & 0xFFFFFFFFu);
        }
    }
}

// ---- final: gkeys -> (dist, idx) ----
__global__ __launch_bounds__(256) void writeout_k(
    const unsigned long long* __restrict__ gkeys, float* __restrict__ out)
{
    const size_t i = (size_t)blockIdx.x * 256 + threadIdx.x;   // 0..2*BN-1
    const unsigned long long m = gkeys[i];
    const int dir = (int)(i / BN);
    const size_t q = i - (size_t)dir * BN;
    out[(size_t)dir * BN + q]       = dec32((uint32_t)(m >> 32));
    out[(size_t)(2 + dir) * BN + q] = (float)(uint32_t)(m & 0xFFFFFFFFu);
}

extern "C" void kernel_launch(void* const* d_in, const int* in_sizes, int n_in,
                              void* d_out, int out_size, void* d_ws, size_t ws_size,
                              hipStream_t stream) {
    const float* xyz1 = (const float*)d_in[0];
    const float* xyz2 = (const float*)d_in[1];
    float* out = (float*)d_out;

    if (ws_size >= (size_t)16 * 1024 * 1024) {
        // encA(4) + encB(4) + y4A(2) + y4B(2) + mkey(1) + gkeys(2) = 15 MiB
        uint4*    encA = (uint4*)d_ws;
        uint4*    encB = encA + (size_t)2 * BN;
        float4*   y4A  = (float4*)(encB + (size_t)2 * BN);
        float4*   y4B  = y4A + BN;
        uint32_t* mkey = (uint32_t*)(y4B + BN);
        unsigned long long* gkeys = (unsigned long long*)(mkey + (size_t)2 * BN);

        enc_kernel<<<BN / 256, 256, 0, stream>>>(xyz2, encA, y4A);
        enc_kernel<<<BN / 256, 256, 0, stream>>>(xyz1, encB, y4B);
        hipMemsetAsync(mkey, 0xFF, (size_t)3 * 1024 * 1024, stream);  // mkey+gkeys
        nn_sweep1<<<2048, 256, 0, stream>>>(xyz1, xyz2, encA, encB, mkey, 2);
        nn_sweep2<<<2048, 256, 0, stream>>>(xyz1, xyz2, encA, encB, y4A, y4B,
                                            mkey, gkeys, out, 2);
        writeout_k<<<(2 * BN) / 256, 256, 0, stream>>>(gkeys, out);
    } else {
        // sequential: enc(4) + y4(2) + mkey(1) = 7 MiB, reuse per direction
        uint4*    enc  = (uint4*)d_ws;
        float4*   y4   = (float4*)(enc + (size_t)2 * BN);
        uint32_t* mkey = (uint32_t*)(y4 + BN);

        hipMemsetAsync(mkey, 0xFF, (size_t)1024 * 1024, stream);
        enc_kernel<<<BN / 256, 256, 0, stream>>>(xyz2, enc, y4);
        nn_sweep1<<<1024, 256, 0, stream>>>(xyz1, xyz2, enc, enc, mkey, 1);
        nn_sweep2<<<1024, 256, 0, stream>>>(xyz1, xyz2, enc, enc, y4, y4,
                                            mkey, nullptr, out, 1);
        hipMemsetAsync(mkey, 0xFF, (size_t)1024 * 1024, stream);
        enc_kernel<<<BN / 256, 256, 0, stream>>>(xyz1, enc, y4);
        nn_sweep1<<<1024, 256, 0, stream>>>(xyz1, xyz2, enc, enc, mkey, 1);
        nn_sweep2<<<1024, 256, 0, stream>>>(xyz1, xyz2, enc, enc, y4, y4,
                                            mkey, nullptr, out, 1);
    }
}